// Round 1
// baseline (323.301 us; speedup 1.0000x reference)
//
#include <hip/hip_runtime.h>
#include <stdint.h>

// ---------- types / helpers ----------
typedef __attribute__((ext_vector_type(8))) short bf16x8;
typedef __attribute__((ext_vector_type(4))) float f32x4;

__device__ __forceinline__ unsigned short f2bf(float f){
  unsigned u = __float_as_uint(f);
  u += 0x7FFFu + ((u >> 16) & 1u);          // round-to-nearest-even
  return (unsigned short)(u >> 16);
}
__device__ __forceinline__ float bf2f(unsigned short s){
  return __uint_as_float(((unsigned)s) << 16);
}

// LDS tiles: [rows][64 bf16] = 128 B/row, XOR-swizzled (16B slot ^ row&7)
__device__ __forceinline__ int lds_off(int r, int b){
  return r * 128 + (b ^ ((r & 7) << 4));
}

// stage tile from bf16 global rows: ROWS x 64 elems at (row0, k0)
template<int ROWS, int NT>
__device__ __forceinline__ void stage_bf16(unsigned short* lds, const unsigned short* g,
                                           long row0, long stride, long k0, int tid){
#pragma unroll
  for (int c = tid; c < ROWS * 8; c += NT){
    int r = c >> 3, s = c & 7;
    uint4 v = *(const uint4*)(g + (row0 + r) * stride + k0 + s * 8);
    *(uint4*)((char*)lds + lds_off(r, s * 16)) = v;
  }
}

// stage tile from f32 global rows, converting to bf16
template<int ROWS, int NT>
__device__ __forceinline__ void stage_f32(unsigned short* lds, const float* g,
                                          long row0, long stride, long k0, int tid){
#pragma unroll
  for (int c = tid; c < ROWS * 8; c += NT){
    int r = c >> 3, s = c & 7;
    const float* src = g + (row0 + r) * stride + k0 + s * 8;
    float4 v0 = *(const float4*)(src);
    float4 v1 = *(const float4*)(src + 4);
    unsigned short t[8] = { f2bf(v0.x), f2bf(v0.y), f2bf(v0.z), f2bf(v0.w),
                            f2bf(v1.x), f2bf(v1.y), f2bf(v1.z), f2bf(v1.w) };
    *(uint4*)((char*)lds + lds_off(r, s * 16)) = *(const uint4*)t;
  }
}

// one BK=64 chunk of MFMAs for a 64x64 wave tile at (wm,wn)
__device__ __forceinline__ void mfma_chunk(const unsigned short* ldsA, const unsigned short* ldsB,
                                           int wm, int wn, int lane, f32x4 acc[4][4]){
  int r = lane & 15, gq = lane >> 4;
#pragma unroll
  for (int ks = 0; ks < 2; ++ks){
    bf16x8 a[4], b[4];
    int bb = ks * 64 + gq * 16;
#pragma unroll
    for (int m = 0; m < 4; ++m)
      a[m] = *(const bf16x8*)((const char*)ldsA + lds_off(wm * 64 + m * 16 + r, bb));
#pragma unroll
    for (int n = 0; n < 4; ++n)
      b[n] = *(const bf16x8*)((const char*)ldsB + lds_off(wn * 64 + n * 16 + r, bb));
#pragma unroll
    for (int m = 0; m < 4; ++m)
#pragma unroll
      for (int n = 0; n < 4; ++n)
        acc[m][n] = __builtin_amdgcn_mfma_f32_16x16x32_bf16(a[m], b[n], acc[m][n], 0, 0, 0);
  }
}

// ---------- prep: transpose weights to bf16, init score with bias ----------
__global__ __launch_bounds__(256) void k_prep(const float* Wm, const float* Wn,
    const float* Wr, const float* Wt, const float* Wrg, const float* Wlg, const float* bp,
    unsigned short* WT, unsigned short* WcatT, float* score){
  long id = (long)blockIdx.x * 256 + threadIdx.x;   // 0 .. 1024*512
  if (id < 1024L * 512){
    int n = (int)(id >> 9), k = (int)(id & 511);
    const float* W = (n < 256) ? Wm : ((n < 512) ? Wn : ((n < 768) ? Wr : Wt));
    WT[id] = f2bf(W[(long)k * 256 + (n & 255)]);
  }
  if (id < 256L * 512){
    int n = (int)(id >> 9), k = (int)(id & 511);
    WcatT[id] = f2bf(k < 256 ? Wrg[(long)k * 256 + n] : Wlg[(long)(k - 256) * 256 + n]);
  }
  if (id < 8192) score[id] = bp[0];
}

// ---------- pass A: [xm|xn|xwr|xl] = x @ [Wm|Wn|Wr|Wt]  (M=8192,K=512,N=1024) ----------
__global__ __launch_bounds__(256) void k_gemmA(const float* x, const unsigned short* WT,
    unsigned short* xm, unsigned short* xn, unsigned short* xwrT, unsigned short* xl){
  __shared__ unsigned short ldsA[128 * 64];
  __shared__ unsigned short ldsB[128 * 64];
  int tid = threadIdx.x, lane = tid & 63, w = tid >> 6;
  int wm = w >> 1, wn = w & 1;
  int bm = blockIdx.x, bn = blockIdx.y;       // 64 x 8
  f32x4 acc[4][4];
  f32x4 zero = {0.f, 0.f, 0.f, 0.f};
#pragma unroll
  for (int m = 0; m < 4; ++m)
#pragma unroll
    for (int n = 0; n < 4; ++n) acc[m][n] = zero;

  for (int k0 = 0; k0 < 512; k0 += 64){
    __syncthreads();
    stage_f32<128, 256>(ldsA, x, (long)bm * 128, 512, k0, tid);
    stage_bf16<128, 256>(ldsB, WT, (long)bn * 128, 512, k0, tid);
    __syncthreads();
    mfma_chunk(ldsA, ldsB, wm, wn, lane, acc);
  }
  int r = lane & 15, gq = lane >> 4;
  int i0 = bm * 128 + wm * 64;
  int n0 = bn * 128 + wn * 64;
#pragma unroll
  for (int m = 0; m < 4; ++m){
#pragma unroll
    for (int n = 0; n < 4; ++n){
      int ng = n0 + n * 16 + r;
      int sector = ng >> 8, nc = ng & 255;
      int ib = i0 + m * 16 + gq * 4;
      if (sector == 2){
        unsigned short p[4];
#pragma unroll
        for (int q = 0; q < 4; ++q) p[q] = f2bf(acc[m][n][q]);
        *(uint2*)(xwrT + (long)nc * 8192 + ib) =
            make_uint2((unsigned)p[0] | ((unsigned)p[1] << 16),
                       (unsigned)p[2] | ((unsigned)p[3] << 16));
      } else {
        unsigned short* dst = sector == 0 ? xm : (sector == 1 ? xn : xl);
#pragma unroll
        for (int q = 0; q < 4; ++q)
          dst[(long)(ib + q) * 256 + nc] = f2bf(acc[m][n][q]);
      }
    }
  }
}

// ---------- row norms of xm / xn ----------
__global__ __launch_bounds__(256) void k_norms(const unsigned short* xm, const unsigned short* xn,
                                               float* nm, float* nn){
  int w = threadIdx.x >> 6, lane = threadIdx.x & 63;
  int row = blockIdx.x * 4 + w;               // 0 .. 16384
  const unsigned short* src = (row < 8192) ? xm : xn;
  int rr = row & 8191;
  unsigned short v[4];
  *(uint2*)v = *(const uint2*)(src + (long)rr * 256 + lane * 4);
  float s = 0.f;
#pragma unroll
  for (int t = 0; t < 4; ++t){ float f = bf2f(v[t]); s += f * f; }
#pragma unroll
  for (int o = 32; o; o >>= 1) s += __shfl_xor(s, o);
  if (lane == 0) ((row < 8192) ? nm : nn)[rr] = s;
}

// ---------- pass B1: adj = f(xm @ xn^T)  (M=N=8192, K=256) ----------
__global__ __launch_bounds__(256) void k_adj(const unsigned short* xm, const unsigned short* xn,
                                             const float* nm, const float* nn, float* adj){
  __shared__ unsigned short ldsA[128 * 64];
  __shared__ unsigned short ldsB[128 * 64];
  int tid = threadIdx.x, lane = tid & 63, w = tid >> 6;
  int wm = w >> 1, wn = w & 1;
  int bm = blockIdx.x, bn = blockIdx.y;       // 64 x 64
  f32x4 acc[4][4];
  f32x4 zero = {0.f, 0.f, 0.f, 0.f};
#pragma unroll
  for (int m = 0; m < 4; ++m)
#pragma unroll
    for (int n = 0; n < 4; ++n) acc[m][n] = zero;

  for (int k0 = 0; k0 < 256; k0 += 64){
    __syncthreads();
    stage_bf16<128, 256>(ldsA, xm, (long)bm * 128, 256, k0, tid);
    stage_bf16<128, 256>(ldsB, xn, (long)bn * 128, 256, k0, tid);
    __syncthreads();
    mfma_chunk(ldsA, ldsB, wm, wn, lane, acc);
  }
  int r = lane & 15, gq = lane >> 4;
#pragma unroll
  for (int m = 0; m < 4; ++m){
#pragma unroll
    for (int n = 0; n < 4; ++n){
      long j = (long)bn * 128 + wn * 64 + n * 16 + r;
      float nnj = nn[j];
#pragma unroll
      for (int q = 0; q < 4; ++q){
        long i = (long)bm * 128 + wm * 64 + m * 16 + gq * 4 + q;
        float sq = nm[i] + nnj - 2.f * acc[m][n][q];
        float d = sqrtf(fmaxf(sq, 0.f)) * 0.5f;
        float e = __expf(-d) * (1.f / 128.f);
        adj[i * 8192 + j] = (i == j) ? 1.f : e;
      }
    }
  }
}

// ---------- pass B2: xr_partial = adj @ xwr  (M=8192, K=8192 split, N=256) ----------
__global__ __launch_bounds__(512) void k_xr(const float* adj, const unsigned short* xwrT,
                                            float* partial, int klen){
  __shared__ unsigned short ldsA[128 * 64];   // adj tile (bf16)
  __shared__ unsigned short ldsB[256 * 64];   // xwrT tile
  int tid = threadIdx.x, lane = tid & 63, w = tid >> 6;   // 8 waves
  int wm = w >> 2, wn = w & 3;                // 2 x 4 -> 128 x 256
  int bm = blockIdx.x, sp = blockIdx.y;
  long j0 = (long)sp * klen;
  f32x4 acc[4][4];
  f32x4 zero = {0.f, 0.f, 0.f, 0.f};
#pragma unroll
  for (int m = 0; m < 4; ++m)
#pragma unroll
    for (int n = 0; n < 4; ++n) acc[m][n] = zero;

  for (int k0 = 0; k0 < klen; k0 += 64){
    __syncthreads();
    stage_f32<128, 512>(ldsA, adj, (long)bm * 128, 8192, j0 + k0, tid);
    stage_bf16<256, 512>(ldsB, xwrT, 0, 8192, j0 + k0, tid);
    __syncthreads();
    mfma_chunk(ldsA, ldsB, wm, wn, lane, acc);
  }
  int r = lane & 15, gq = lane >> 4;
  float* dst = partial + (long)sp * 8192 * 256;
#pragma unroll
  for (int m = 0; m < 4; ++m){
#pragma unroll
    for (int n = 0; n < 4; ++n){
      int c = wn * 64 + n * 16 + r;
#pragma unroll
      for (int q = 0; q < 4; ++q){
        long i = (long)bm * 128 + wm * 64 + m * 16 + gq * 4 + q;
        dst[i * 256 + c] = acc[m][n][q];
      }
    }
  }
}

// ---------- reduce split-K partials -> xr (bf16) ----------
__global__ __launch_bounds__(256) void k_reduce_xr(const float* partial, unsigned short* xr, int S){
  long idx = ((long)blockIdx.x * 256 + threadIdx.x) * 4;   // 4 f32 each; grid covers exactly
  float4 a = *(const float4*)(partial + idx);
  for (int s = 1; s < S; ++s){
    const float4 b = *(const float4*)(partial + (long)s * 8192 * 256 + idx);
    a.x += b.x; a.y += b.y; a.z += b.z; a.w += b.w;
  }
  unsigned short p[4] = { f2bf(a.x), f2bf(a.y), f2bf(a.z), f2bf(a.w) };
  *(uint2*)(xr + idx) = make_uint2((unsigned)p[0] | ((unsigned)p[1] << 16),
                                   (unsigned)p[2] | ((unsigned)p[3] << 16));
}

// ---------- pass C: w = sigmoid([xr|xl]@[Wrg;Wlg] + b), feat, score ----------
__global__ __launch_bounds__(512) void k_gate(const unsigned short* xr, const unsigned short* xl,
    const unsigned short* WcatT, const float* brg, const float* blg,
    const float* Wp, float* score){
  __shared__ unsigned short ldsA[128 * 64];
  __shared__ unsigned short ldsB[256 * 64];
  int tid = threadIdx.x, lane = tid & 63, w = tid >> 6;
  int wm = w >> 2, wn = w & 3;                // 2 x 4 -> 128 x 256
  int bm = blockIdx.x;                        // 64 blocks
  f32x4 acc[4][4];
  f32x4 zero = {0.f, 0.f, 0.f, 0.f};
#pragma unroll
  for (int m = 0; m < 4; ++m)
#pragma unroll
    for (int n = 0; n < 4; ++n) acc[m][n] = zero;

  for (int k0 = 0; k0 < 512; k0 += 64){
    const unsigned short* A = (k0 < 256) ? xr : xl;
    __syncthreads();
    stage_bf16<128, 512>(ldsA, A, (long)bm * 128, 256, k0 & 255, tid);
    stage_bf16<256, 512>(ldsB, WcatT, 0, 512, k0, tid);
    __syncthreads();
    mfma_chunk(ldsA, ldsB, wm, wn, lane, acc);
  }
  int r = lane & 15, gq = lane >> 4;
#pragma unroll
  for (int m = 0; m < 4; ++m){
#pragma unroll
    for (int q = 0; q < 4; ++q){
      long i = (long)bm * 128 + wm * 64 + m * 16 + gq * 4 + q;
      float part = 0.f;
#pragma unroll
      for (int n = 0; n < 4; ++n){
        int c = wn * 64 + n * 16 + r;
        float arg = acc[m][n][q] + brg[c] + blg[c];
        float wv = 1.f / (1.f + __expf(-arg));
        float xrv = bf2f(xr[i * 256 + c]);
        float xlv = bf2f(xl[i * 256 + c]);
        float feat = (1.f - wv) * xrv + wv * xlv;
        part += feat * Wp[c];
      }
      part += __shfl_xor(part, 1);
      part += __shfl_xor(part, 2);
      part += __shfl_xor(part, 4);
      part += __shfl_xor(part, 8);
      if (r == 0) atomicAdd(score + i, part);
    }
  }
}

// ---------- host ----------
extern "C" void kernel_launch(void* const* d_in, const int* in_sizes, int n_in,
                              void* d_out, int out_size, void* d_ws, size_t ws_size,
                              hipStream_t stream){
  const float* x   = (const float*)d_in[0];
  const float* Wm  = (const float*)d_in[1];
  const float* Wn  = (const float*)d_in[2];
  const float* Wr  = (const float*)d_in[3];
  const float* Wt  = (const float*)d_in[4];
  const float* Wrg = (const float*)d_in[5];
  const float* brg = (const float*)d_in[6];
  const float* Wlg = (const float*)d_in[7];
  const float* blg = (const float*)d_in[8];
  const float* Wp  = (const float*)d_in[9];
  const float* bp  = (const float*)d_in[10];

  float* adj   = (float*)d_out;
  float* score = adj + 8192L * 8192;

  char* wsb = (char*)d_ws;
  unsigned short* xm    = (unsigned short*)(wsb);                 // 4 MB
  unsigned short* xn    = (unsigned short*)(wsb + (4L  << 20));   // 4 MB
  unsigned short* xwrT  = (unsigned short*)(wsb + (8L  << 20));   // 4 MB [256][8192]
  unsigned short* xl    = (unsigned short*)(wsb + (12L << 20));   // 4 MB
  unsigned short* xr    = (unsigned short*)(wsb + (16L << 20));   // 4 MB
  float*          nm    = (float*)         (wsb + (20L << 20));   // 32 KB
  float*          nn    = nm + 8192;                              // 32 KB
  unsigned short* WT    = (unsigned short*)(wsb + (21L << 20));   // 1 MB [1024][512]
  unsigned short* WcatT = (unsigned short*)(wsb + (22L << 20));   // 256 KB [256][512]
  float*          partial = (float*)(wsb + (23L << 20));          // S * 8 MB

  int S = 1;
  size_t base = 23L << 20;
  if      (ws_size >= base + 4 * (8L << 20)) S = 4;
  else if (ws_size >= base + 2 * (8L << 20)) S = 2;

  k_prep  <<<2048, 256, 0, stream>>>(Wm, Wn, Wr, Wt, Wrg, Wlg, bp, WT, WcatT, score);
  k_gemmA <<<dim3(64, 8), 256, 0, stream>>>(x, WT, xm, xn, xwrT, xl);
  k_norms <<<4096, 256, 0, stream>>>(xm, xn, nm, nn);
  k_adj   <<<dim3(64, 64), 256, 0, stream>>>(xm, xn, nm, nn, adj);
  k_xr    <<<dim3(64, S), 512, 0, stream>>>(adj, xwrT, partial, 8192 / S);
  k_reduce_xr<<<2048, 256, 0, stream>>>(partial, xr, S);
  k_gate  <<<64, 512, 0, stream>>>(xr, xl, WcatT, brg, blg, Wp, score);
}